// Round 7
// baseline (81.233 us; speedup 1.0000x reference)
//
#include <hip/hip_runtime.h>

#define NB 64        // bins
#define HW 65536     // pixels per channel (256*256)
#define NCH 24       // B*C = 8*3
#define SPLIT 16     // segments per channel-image
#define NPAIR 38     // 76 slots as 38 float2 pairs; slot = bin + 6, bins -6..69

// w_j(x) = exp(-K*(f-j)^2), f = 63x, K = 2048/3969.
// Even-aligned 12-tap window: e0 = (rint(f)-5) & ~1, c0 = e0+6,
// d' = f - c0 in [-1.5, 0.5]; taps r = -6..5 -> bins e0..e0+11 (superset of
// the +-5 window; dropped mass < 1.5e-7 relative). 3 transcendentals, 12 taps.
//
// r7 structural change: PING-PONG private copies. 128 threads/block, each
// thread owns TWO 38-pair histogram copies in DISTINCT __shared__ arrays
// (HA/HB), alternating per pixel (parity static after unroll). Distinct
// objects => provable no-alias => the compiler may hoist pixel e+1's reads
// (other array) above pixel e's writes and use counted lgkmcnt waits: two
// pixels' DS round-trips + ladders overlap instead of serializing (r0-r6
// evidence: all same-array variants stuck at ~22-33us with VALUBusy ~5% —
// latency-chained, not DS-issue-bound). Within one array consecutive uses
// stay program-ordered; DS completes in order per wave => RAW-safe.
// LDS: 2 x 38x128 float2 = 77824 B -> 2 blocks/CU, bank pattern (2*tid)%32
// uniform b64. No atomics (r1), no device fences (r3).
__global__ __launch_bounds__(128) void chml_hist(const float* __restrict__ pred,
                                                 const float* __restrict__ targ,
                                                 float* __restrict__ part) {
  const int seg = blockIdx.x;   // 0..SPLIT-1
  const int ct  = blockIdx.y;   // 0..2*NCH-1
  const float* src = (ct < NCH) ? (pred + (size_t)ct * HW)
                                : (targ + (size_t)(ct - NCH) * HW);
  const int tid = threadIdx.x;  // 0..127

  // segment = 4096 px = 1024 float4; 128 threads x 8 float4, issued up front
  const float4* s4 = (const float4*)(src + (size_t)seg * (HW / SPLIT));
  float4 P[8];
#pragma unroll
  for (int i = 0; i < 8; ++i) P[i] = s4[i * 128 + tid];

  __shared__ float2 HA[NPAIR][128];   // 38912 B
  __shared__ float2 HB[NPAIR][128];   // 38912 B
  {
    float4* za = (float4*)&HA[0][0];
    float4* zb = (float4*)&HB[0][0];
#pragma unroll
    for (int i = tid; i < NPAIR * 128 * 2 / 4; i += 128) {
      za[i] = make_float4(0.f, 0.f, 0.f, 0.f);
      zb[i] = make_float4(0.f, 0.f, 0.f, 0.f);
    }
  }
  __syncthreads();

  const float K  = 0.51599899f;      // 2048/3969
  const float C1 = 5.96905619e-01f;  // exp(-K*1)
  const float C2 = 1.26927917e-01f;  // exp(-K*4)
  const float C3 = 9.61165782e-03f;  // exp(-K*9)
  const float C4 = 2.59240329e-04f;  // exp(-K*16)
  const float C5 = 2.49029640e-06f;  // exp(-K*25)
  const float C6 = 8.56260000e-09f;  // exp(-K*36)

  float2* const hbA = &HA[0][tid];   // pair stride = 128 float2 = 1024 B
  float2* const hbB = &HB[0][tid];

#pragma unroll
  for (int k2 = 0; k2 < 8; ++k2) {
    float4 p = P[k2];
    float pe[4] = {p.x, p.y, p.z, p.w};
#pragma unroll
    for (int e = 0; e < 4; ++e) {
      float f  = pe[e] * 63.0f;
      float n  = rintf(f);
      int   ni = (int)n;                        // 0..63
      int   e0 = (ni - 5) & ~1;                 // even, in [-6, 58]
      float dp = f - (float)(e0 + 6);           // d' in [-1.5, 0.5]
      float2* tp = ((e & 1) ? hbB : hbA) + (((e0 >> 1) + 3) << 7);
      // ---- issue the 6 b64 tap reads (alternating arrays across pixels)
      float2 t[6];
#pragma unroll
      for (int j = 0; j < 6; ++j) t[j] = tp[j * 128];
      // ---- weight ladder (independent of the reads)
      float w0 = __expf(dp * dp * -K);
      float mp = __expf(dp * (2.0f * K));
      float mn = __expf(dp * (-2.0f * K));
      float mp2 = mp * mp, mp3 = mp2 * mp, mp4 = mp2 * mp2, mp5 = mp4 * mp;
      float mn2 = mn * mn, mn3 = mn2 * mn, mn4 = mn2 * mn2, mn5 = mn4 * mn,
            mn6 = mn3 * mn3;
      float A1 = w0 * C1, A2 = w0 * C2, A3 = w0 * C3, A4 = w0 * C4,
            A5 = w0 * C5, A6 = w0 * C6;
      float2 w[6];
      w[0] = make_float2(A6 * mn6, A5 * mn5);  // r = -6, -5
      w[1] = make_float2(A4 * mn4, A3 * mn3);
      w[2] = make_float2(A2 * mn2, A1 * mn);
      w[3] = make_float2(w0,       A1 * mp);   // r = 0, +1
      w[4] = make_float2(A2 * mp2, A3 * mp3);
      w[5] = make_float2(A4 * mp4, A5 * mp5);  // r = +4, +5
      // ---- RMW writeback (6 ds_write_b64)
#pragma unroll
      for (int j = 0; j < 6; ++j)
        tp[j * 128] = make_float2(t[j].x + w[j].x, t[j].y + w[j].y);
    }
  }
  __syncthreads();

  // Fold: wave 0 folds HA's 128 columns, wave 1 folds HB's. Lane l (<38)
  // owns pair l; staggered col order (i+l)&127 -> uniform b64 banks.
  const int wv = tid >> 6, l = tid & 63;
  float2 facc = make_float2(0.f, 0.f);
  if (l < NPAIR) {
    const float2* col = wv ? &HB[l][0] : &HA[l][0];
#pragma unroll 8
    for (int i = 0; i < 128; ++i) {
      float2 v = col[(i + l) & 127];
      facc.x += v.x; facc.y += v.y;
    }
  }
  __syncthreads();
  if (l < NPAIR) HA[l][wv] = facc;   // scratch (HA already consumed)
  __syncthreads();
  if (tid < NPAIR) {
    float2 a = HA[tid][0], b2 = HA[tid][1];
    float sx = a.x + b2.x;
    float sy = a.y + b2.y;
    int bin0 = 2 * tid - 6;          // slot 2*tid -> bin = slot - 6
    float* dst = part + ((size_t)ct * SPLIT + seg) * NB;
    if (bin0 >= 0 && bin0 < NB) dst[bin0] = sx;
    int bin1 = bin0 + 1;
    if (bin1 >= 0 && bin1 < NB) dst[bin1] = sy;
  }
}

// Merged tail: per-channel CDF loss + atomic accumulation into out.
// 24 blocks x 64 threads (parallel across CUs — r5 lesson); out zeroed by a
// 4-byte hipMemsetAsync. Pre-scaled atomicAdd replaces the chml_final launch.
__global__ __launch_bounds__(64) void chml_chan(const float* __restrict__ part,
                                                float* __restrict__ out) {
  const int c    = blockIdx.x;
  const int lane = threadIdx.x;
  float vp = 0.0f, vt = 0.0f;
#pragma unroll
  for (int s = 0; s < SPLIT; ++s) {
    vp += part[((size_t)c * SPLIT + s) * NB + lane];
    vt += part[((size_t)(c + NCH) * SPLIT + s) * NB + lane];
  }
  // inclusive prefix scan across 64 lanes
#pragma unroll
  for (int off = 1; off < 64; off <<= 1) {
    float up = __shfl_up(vp, off, 64);
    float ut = __shfl_up(vt, off, 64);
    if (lane >= off) { vp += up; vt += ut; }
  }
  float totp = __shfl(vp, 63, 64);
  float tott = __shfl(vt, 63, 64);
  float l = fabsf(vp / (totp + 1e-7f) - vt / (tott + 1e-7f));
#pragma unroll
  for (int off = 32; off >= 1; off >>= 1) l += __shfl_xor(l, off, 64);
  if (lane == 0) atomicAdd(out, l * (1.0f / (float)(NCH * NB)));
}

extern "C" void kernel_launch(void* const* d_in, const int* in_sizes, int n_in,
                              void* d_out, int out_size, void* d_ws, size_t ws_size,
                              hipStream_t stream) {
  const float* pred = (const float*)d_in[0];
  const float* targ = (const float*)d_in[1];
  float* part = (float*)d_ws;        // 48*16*64 floats = 196 KB

  hipMemsetAsync(d_out, 0, sizeof(float), stream);
  dim3 grid(SPLIT, 2 * NCH);
  chml_hist<<<grid, 128, 0, stream>>>(pred, targ, part);
  chml_chan<<<NCH, 64, 0, stream>>>(part, (float*)d_out);
}

// Round 8
// 74.751 us; speedup vs baseline: 1.0867x; 1.0867x over previous
//
#include <hip/hip_runtime.h>

#define NB 64        // bins
#define HW 65536     // pixels per channel (256*256)
#define NCH 24       // B*C = 8*3
#define SPLIT 8      // segments per channel-image
#define NPAIR 38     // 76 slots as 38 float2 pairs; slot = bin + 6, bins -6..69

// w_j(x) = exp(-K*(f-j)^2), f = 63x, K = 2048/3969.
// Even-aligned 12-tap window: e0 = (rint(f)-5) & ~1, c0 = e0+6,
// d' = f - c0 in [-1.5, 0.5]; taps r = -6..5 -> bins e0..e0+11 (superset of
// the +-5 window; dropped mass < 1.5e-7 relative). 3 transcendentals, 12 taps.
//
// LDS: H[pair][256] float2 -> a pixel's 12 taps = 6 ALIGNED float2 cells at
// stride 2048 B => 6 ds_read_b64 + 6 ds_write_b64 (imm offsets), bank pattern
// (2*tid+{0,1})%32 uniform. Private per-thread columns => no atomics, no races;
// same-wave DS ops complete in order => per-pixel RMW is RAW-safe.
//
// r8 change (single variable vs r6): sched_group_barrier pins per pixel.
// Theory: in the fully-unrolled 32-pixel body the scheduler SINKS the tap
// reads down to their uses (after the ladder), serializing
// ladder -> reads -> full ~120cy wait -> writes per pixel (~270cy, matches
// the measured 22us at 2 waves/SIMD). The pins force the source order
// R(i) -> ladder(i) [covers read latency] -> W(i) -> R(i+1), which should
// approach the ~5us DS-issue floor. SGB is a pure scheduling hint — no
// correctness risk (masks: DS_READ=0x100, ALU=0x1, DS_WRITE=0x200).
__global__ __launch_bounds__(256) void chml_hist(const float* __restrict__ pred,
                                                 const float* __restrict__ targ,
                                                 float* __restrict__ part) {
  const int seg = blockIdx.x;   // 0..SPLIT-1
  const int ct  = blockIdx.y;   // 0..2*NCH-1
  const float* src = (ct < NCH) ? (pred + (size_t)ct * HW)
                                : (targ + (size_t)(ct - NCH) * HW);
  const int tid = threadIdx.x;

  // issue all 8 global float4 loads first (in flight during LDS init)
  const float4* s4 = (const float4*)(src + (size_t)seg * (HW / SPLIT));
  float4 P[8];
#pragma unroll
  for (int i = 0; i < 8; ++i) P[i] = s4[i * 256 + tid];

  __shared__ float2 H[NPAIR][256];   // 77824 B -> 2 blocks/CU
  {
    float4* hz = (float4*)&H[0][0];
#pragma unroll
    for (int i = tid; i < NPAIR * 256 * 2 / 4; i += 256)
      hz[i] = make_float4(0.f, 0.f, 0.f, 0.f);
  }
  __syncthreads();

  const float K  = 0.51599899f;      // 2048/3969
  const float C1 = 5.96905619e-01f;  // exp(-K*1)
  const float C2 = 1.26927917e-01f;  // exp(-K*4)
  const float C3 = 9.61165782e-03f;  // exp(-K*9)
  const float C4 = 2.59240329e-04f;  // exp(-K*16)
  const float C5 = 2.49029640e-06f;  // exp(-K*25)
  const float C6 = 8.56260000e-09f;  // exp(-K*36)

  float2* const hb = &H[0][tid];     // pair stride = 256 float2 = 2048 B

#pragma unroll
  for (int k2 = 0; k2 < 8; ++k2) {
    float4 p = P[k2];
    float pe[4] = {p.x, p.y, p.z, p.w};
#pragma unroll
    for (int e = 0; e < 4; ++e) {
      float f  = pe[e] * 63.0f;
      float n  = rintf(f);
      int   ni = (int)n;                        // 0..63
      int   e0 = (ni - 5) & ~1;                 // even, in [-6, 58]
      float dp = f - (float)(e0 + 6);           // d' in [-1.5, 0.5]
      float2* tp = hb + (((e0 >> 1) + 3) << 8); // pair p0 = (e0+6)/2 in [0,32]
      // ---- 6 b64 tap reads: pinned HERE (before the ladder) by SGB
      float2 t[6];
#pragma unroll
      for (int j = 0; j < 6; ++j) t[j] = tp[j * 256];
      __builtin_amdgcn_sched_group_barrier(0x100, 6, 0);   // 6 DS_READ
      // ---- weight ladder (independent of the reads -> overlaps latency)
      float w0 = __expf(dp * dp * -K);
      float mp = __expf(dp * (2.0f * K));
      float mn = __expf(dp * (-2.0f * K));
      float mp2 = mp * mp, mp3 = mp2 * mp, mp4 = mp2 * mp2, mp5 = mp4 * mp;
      float mn2 = mn * mn, mn3 = mn2 * mn, mn4 = mn2 * mn2, mn5 = mn4 * mn,
            mn6 = mn3 * mn3;
      float A1 = w0 * C1, A2 = w0 * C2, A3 = w0 * C3, A4 = w0 * C4,
            A5 = w0 * C5, A6 = w0 * C6;
      float2 w[6];
      w[0] = make_float2(A6 * mn6, A5 * mn5);  // r = -6, -5
      w[1] = make_float2(A4 * mn4, A3 * mn3);
      w[2] = make_float2(A2 * mn2, A1 * mn);
      w[3] = make_float2(w0,       A1 * mp);   // r = 0, +1
      w[4] = make_float2(A2 * mp2, A3 * mp3);
      w[5] = make_float2(A4 * mp4, A5 * mp5);  // r = +4, +5
      __builtin_amdgcn_sched_group_barrier(0x001, 48, 0);  // ladder+adds ALU
      // ---- RMW writeback (6 ds_write_b64), pinned after the ALU group
#pragma unroll
      for (int j = 0; j < 6; ++j)
        tp[j * 256] = make_float2(t[j].x + w[j].x, t[j].y + w[j].y);
      __builtin_amdgcn_sched_group_barrier(0x200, 6, 0);   // 6 DS_WRITE
    }
  }
  __syncthreads();

  // Fold 256 columns -> 1 per pair. Lane l (<38) owns pair l; wave wv sums
  // rows [64wv, 64wv+64) with staggered row order (i+l)&63 -> uniform b64
  // banks, conflict-free.
  const int wv = tid >> 6, l = tid & 63;
  float2 facc = make_float2(0.f, 0.f);
  if (l < NPAIR) {
    const float2* col = &H[l][wv << 6];
#pragma unroll 8
    for (int i = 0; i < 64; ++i) {
      float2 v = col[(i + l) & 63];
      facc.x += v.x; facc.y += v.y;
    }
  }
  __syncthreads();
  if (l < NPAIR) H[l][wv] = facc;   // scratch: rows 0..3 (already consumed)
  __syncthreads();
  if (tid < NPAIR) {
    float2 a = H[tid][0], b2 = H[tid][1], c2 = H[tid][2], d2 = H[tid][3];
    float sx = a.x + b2.x + c2.x + d2.x;
    float sy = a.y + b2.y + c2.y + d2.y;
    int bin0 = 2 * tid - 6;          // slot 2*tid -> bin = slot - 6
    float* dst = part + ((size_t)ct * SPLIT + seg) * NB;
    if (bin0 >= 0 && bin0 < NB) dst[bin0] = sx;
    int bin1 = bin0 + 1;
    if (bin1 >= 0 && bin1 < NB) dst[bin1] = sy;
  }
}

// Per-channel: sum segment partials, normalize, cumsum, sum |cdf diff|.
// 24 blocks x 64 threads (parallel across CUs — r5 lesson). Writes chanloss[c].
__global__ __launch_bounds__(64) void chml_chan(const float* __restrict__ part,
                                                float* __restrict__ chanloss) {
  const int c    = blockIdx.x;
  const int lane = threadIdx.x;
  float vp = 0.0f, vt = 0.0f;
#pragma unroll
  for (int s = 0; s < SPLIT; ++s) {
    vp += part[((size_t)c * SPLIT + s) * NB + lane];
    vt += part[((size_t)(c + NCH) * SPLIT + s) * NB + lane];
  }
  // inclusive prefix scan across 64 lanes
#pragma unroll
  for (int off = 1; off < 64; off <<= 1) {
    float up = __shfl_up(vp, off, 64);
    float ut = __shfl_up(vt, off, 64);
    if (lane >= off) { vp += up; vt += ut; }
  }
  float totp = __shfl(vp, 63, 64);
  float tott = __shfl(vt, 63, 64);
  float l = fabsf(vp / (totp + 1e-7f) - vt / (tott + 1e-7f));
#pragma unroll
  for (int off = 32; off >= 1; off >>= 1) l += __shfl_xor(l, off, 64);
  if (lane == 0) chanloss[c] = l;
}

// Final: mean over 24*64 terms.
__global__ __launch_bounds__(64) void chml_final(const float* __restrict__ chanloss,
                                                 float* __restrict__ out) {
  const int lane = threadIdx.x;
  float l = (lane < NCH) ? chanloss[lane] : 0.0f;
#pragma unroll
  for (int off = 32; off >= 1; off >>= 1) l += __shfl_xor(l, off, 64);
  if (lane == 0) out[0] = l * (1.0f / (float)(NCH * NB));
}

extern "C" void kernel_launch(void* const* d_in, const int* in_sizes, int n_in,
                              void* d_out, int out_size, void* d_ws, size_t ws_size,
                              hipStream_t stream) {
  const float* pred = (const float*)d_in[0];
  const float* targ = (const float*)d_in[1];
  float* part     = (float*)d_ws;                        // 48*8*64 floats = 96 KB
  float* chanloss = part + (size_t)2 * NCH * SPLIT * NB; // +24 floats

  dim3 grid(SPLIT, 2 * NCH);
  chml_hist<<<grid, 256, 0, stream>>>(pred, targ, part);
  chml_chan<<<NCH, 64, 0, stream>>>(part, chanloss);
  chml_final<<<1, 64, 0, stream>>>(chanloss, (float*)d_out);
}

// Round 9
// 72.341 us; speedup vs baseline: 1.1229x; 1.0333x over previous
//
#include <hip/hip_runtime.h>

#define NB 64        // bins
#define HW 65536     // pixels per channel (256*256)
#define NCH 24       // B*C = 8*3
#define SPLIT 8      // segments per channel-image
#define NPAIR 38     // 76 slots as 38 float2 pairs; slot = bin + 6, bins -6..69

// w_j(x) = exp(-K*(f-j)^2), f = 63x, K = 2048/3969.
// Even-aligned 12-tap window: e0 = (rint(f)-5) & ~1, c0 = e0+6,
// d' = f - c0 in [-1.5, 0.5]; taps r = -6..5 -> bins e0..e0+11 (superset of
// the +-5 window; dropped mass < 1.5e-7 relative). 3 transcendentals, 12 taps.
//
// LDS: H[pair][256] float2 -> a pixel's 12 taps = 6 ALIGNED float2 cells at
// stride 2048 B => 6 ds_read_b64 + 6 ds_write_b64 (imm offsets), bank pattern
// (2*tid+{0,1})%32 uniform. Private per-thread columns => no atomics, no races;
// same-wave DS ops complete in order => per-pixel RMW is RAW-safe.
//
// Negative results codified (do NOT revisit):
//   r1: LDS float atomics ~200cy each.  r3: device fences/completion atomics
//   in the big kernel ~90us.  r5: 1-block tail serializes ~768 L2 loads.
//   r7: 128-thread blocks -> 1 wave/SIMD, latency exposed.  r8: SGB pins null.
// r9 change: 3 dispatches -> 2. chml_final folded into chml_chan via
// pre-scaled atomicAdd; d_out zeroed by hist block (0,0) (stream-ordered,
// no extra memset dispatch).
__global__ __launch_bounds__(256) void chml_hist(const float* __restrict__ pred,
                                                 const float* __restrict__ targ,
                                                 float* __restrict__ part,
                                                 float* __restrict__ out) {
  const int seg = blockIdx.x;   // 0..SPLIT-1
  const int ct  = blockIdx.y;   // 0..2*NCH-1
  const float* src = (ct < NCH) ? (pred + (size_t)ct * HW)
                                : (targ + (size_t)(ct - NCH) * HW);
  const int tid = threadIdx.x;

  if (seg == 0 && ct == 0 && tid == 0) out[0] = 0.0f;  // for chan's atomicAdd

  // issue all 8 global float4 loads first (in flight during LDS init)
  const float4* s4 = (const float4*)(src + (size_t)seg * (HW / SPLIT));
  float4 P[8];
#pragma unroll
  for (int i = 0; i < 8; ++i) P[i] = s4[i * 256 + tid];

  __shared__ float2 H[NPAIR][256];   // 77824 B -> 2 blocks/CU
  {
    float4* hz = (float4*)&H[0][0];
#pragma unroll
    for (int i = tid; i < NPAIR * 256 * 2 / 4; i += 256)
      hz[i] = make_float4(0.f, 0.f, 0.f, 0.f);
  }
  __syncthreads();

  const float K  = 0.51599899f;      // 2048/3969
  const float C1 = 5.96905619e-01f;  // exp(-K*1)
  const float C2 = 1.26927917e-01f;  // exp(-K*4)
  const float C3 = 9.61165782e-03f;  // exp(-K*9)
  const float C4 = 2.59240329e-04f;  // exp(-K*16)
  const float C5 = 2.49029640e-06f;  // exp(-K*25)
  const float C6 = 8.56260000e-09f;  // exp(-K*36)

  float2* const hb = &H[0][tid];     // pair stride = 256 float2 = 2048 B

#pragma unroll
  for (int k2 = 0; k2 < 8; ++k2) {
    float4 p = P[k2];
    float pe[4] = {p.x, p.y, p.z, p.w};
#pragma unroll
    for (int e = 0; e < 4; ++e) {
      float f  = pe[e] * 63.0f;
      float n  = rintf(f);
      int   ni = (int)n;                        // 0..63
      int   e0 = (ni - 5) & ~1;                 // even, in [-6, 58]
      float dp = f - (float)(e0 + 6);           // d' in [-1.5, 0.5]
      float2* tp = hb + (((e0 >> 1) + 3) << 8); // pair p0 = (e0+6)/2 in [0,32]
      // ---- issue the 6 b64 tap reads first (latency hidden by the ladder)
      float2 t[6];
#pragma unroll
      for (int j = 0; j < 6; ++j) t[j] = tp[j * 256];
      // ---- weight ladder (independent of the reads)
      float w0 = __expf(dp * dp * -K);
      float mp = __expf(dp * (2.0f * K));
      float mn = __expf(dp * (-2.0f * K));
      float mp2 = mp * mp, mp3 = mp2 * mp, mp4 = mp2 * mp2, mp5 = mp4 * mp;
      float mn2 = mn * mn, mn3 = mn2 * mn, mn4 = mn2 * mn2, mn5 = mn4 * mn,
            mn6 = mn3 * mn3;
      float A1 = w0 * C1, A2 = w0 * C2, A3 = w0 * C3, A4 = w0 * C4,
            A5 = w0 * C5, A6 = w0 * C6;
      float2 w[6];
      w[0] = make_float2(A6 * mn6, A5 * mn5);  // r = -6, -5
      w[1] = make_float2(A4 * mn4, A3 * mn3);
      w[2] = make_float2(A2 * mn2, A1 * mn);
      w[3] = make_float2(w0,       A1 * mp);   // r = 0, +1
      w[4] = make_float2(A2 * mp2, A3 * mp3);
      w[5] = make_float2(A4 * mp4, A5 * mp5);  // r = +4, +5
      // ---- RMW writeback (6 ds_write_b64)
#pragma unroll
      for (int j = 0; j < 6; ++j)
        tp[j * 256] = make_float2(t[j].x + w[j].x, t[j].y + w[j].y);
    }
  }
  __syncthreads();

  // Fold 256 columns -> 1 per pair. Lane l (<38) owns pair l; wave wv sums
  // rows [64wv, 64wv+64) with staggered row order (i+l)&63 -> uniform b64
  // banks, conflict-free.
  const int wv = tid >> 6, l = tid & 63;
  float2 facc = make_float2(0.f, 0.f);
  if (l < NPAIR) {
    const float2* col = &H[l][wv << 6];
#pragma unroll 8
    for (int i = 0; i < 64; ++i) {
      float2 v = col[(i + l) & 63];
      facc.x += v.x; facc.y += v.y;
    }
  }
  __syncthreads();
  if (l < NPAIR) H[l][wv] = facc;   // scratch: rows 0..3 (already consumed)
  __syncthreads();
  if (tid < NPAIR) {
    float2 a = H[tid][0], b2 = H[tid][1], c2 = H[tid][2], d2 = H[tid][3];
    float sx = a.x + b2.x + c2.x + d2.x;
    float sy = a.y + b2.y + c2.y + d2.y;
    int bin0 = 2 * tid - 6;          // slot 2*tid -> bin = slot - 6
    float* dst = part + ((size_t)ct * SPLIT + seg) * NB;
    if (bin0 >= 0 && bin0 < NB) dst[bin0] = sx;
    int bin1 = bin0 + 1;
    if (bin1 >= 0 && bin1 < NB) dst[bin1] = sy;
  }
}

// Merged tail: per-channel CDF loss, pre-scaled atomicAdd into out.
// 24 blocks x 64 threads (parallel across CUs — r5 lesson). out was zeroed
// by hist block (0,0); stream order makes this race-free. 24 same-address
// device atomics: trivial cost, no fences needed.
__global__ __launch_bounds__(64) void chml_chan(const float* __restrict__ part,
                                                float* __restrict__ out) {
  const int c    = blockIdx.x;
  const int lane = threadIdx.x;
  float vp = 0.0f, vt = 0.0f;
#pragma unroll
  for (int s = 0; s < SPLIT; ++s) {
    vp += part[((size_t)c * SPLIT + s) * NB + lane];
    vt += part[((size_t)(c + NCH) * SPLIT + s) * NB + lane];
  }
  // inclusive prefix scan across 64 lanes
#pragma unroll
  for (int off = 1; off < 64; off <<= 1) {
    float up = __shfl_up(vp, off, 64);
    float ut = __shfl_up(vt, off, 64);
    if (lane >= off) { vp += up; vt += ut; }
  }
  float totp = __shfl(vp, 63, 64);
  float tott = __shfl(vt, 63, 64);
  float l = fabsf(vp / (totp + 1e-7f) - vt / (tott + 1e-7f));
#pragma unroll
  for (int off = 32; off >= 1; off >>= 1) l += __shfl_xor(l, off, 64);
  if (lane == 0) atomicAdd(out, l * (1.0f / (float)(NCH * NB)));
}

extern "C" void kernel_launch(void* const* d_in, const int* in_sizes, int n_in,
                              void* d_out, int out_size, void* d_ws, size_t ws_size,
                              hipStream_t stream) {
  const float* pred = (const float*)d_in[0];
  const float* targ = (const float*)d_in[1];
  float* part = (float*)d_ws;        // 48*8*64 floats = 96 KB

  dim3 grid(SPLIT, 2 * NCH);
  chml_hist<<<grid, 256, 0, stream>>>(pred, targ, part, (float*)d_out);
  chml_chan<<<NCH, 64, 0, stream>>>(part, (float*)d_out);
}